// Round 16
// baseline (106.406 us; speedup 1.0000x reference)
//
#include <hip/hip_runtime.h>

#define NORIENT 8

// XCD-aware block swizzle (bijective when gridDim % 8 == 0; all our grids are).
__device__ __forceinline__ unsigned xcd_swz(unsigned bid, unsigned nwg) {
    unsigned chunk = nwg >> 3;
    return (nwg & 7u) ? bid : (bid & 7u) * chunk + (bid >> 3);
}

__device__ __forceinline__ float bf2f(unsigned short u) {
    return __uint_as_float((unsigned)u << 16);
}
__device__ __forceinline__ unsigned short f2bf(float f) {   // round-to-nearest-even
    unsigned b = __float_as_uint(f);
    return (unsigned short)((b + 0x7FFFu + ((b >> 16) & 1u)) >> 16);
}

// -------- forward level 1, wave-per-channel: ch0 -> fp32, ch1-7 -> bf16 --------
// (R12-proven body; only the store path differs per wave — wave-uniform branch.)
__global__ void fwd_conv_wave_l1_kernel(const float* __restrict__ in, long in_img_stride,
                                        const float* __restrict__ filt,
                                        float* __restrict__ outc0,          // [n][256][256] fp32
                                        unsigned short* __restrict__ outb,  // [n][7][256][256] bf16
                                        int H, int W, int OH, int OW, int N) {
    constexpr int SROW = 104;
    __shared__ float tile[67 * SROW];

    int nbx = OW >> 5, nby = OH >> 5;
    unsigned sb = xcd_swz(blockIdx.x, gridDim.x);
    int bx = (int)(sb % nbx);
    unsigned t = sb / nbx;
    int by = (int)(t % nby);
    int n = (int)(t / nby);

    const float* __restrict__ ip = in + (long)n * in_img_stride;
    int tid = threadIdx.x;

    int w = __builtin_amdgcn_readfirstlane(tid >> 6);
    const float* __restrict__ F = filt + w * 25;
    float Wt[25];
#pragma unroll
    for (int k = 0; k < 25; ++k) Wt[k] = F[k];

    int gy0 = 64 * by - 2, gx0 = 64 * bx - 4;
#pragma unroll
    for (int k = 0; k < 3; ++k) {
        int e = tid + k * 512;
        if (e < 67 * 18) {
            int row = e / 18, m = e - row * 18;
            int gy = gy0 + row, gx = gx0 + 4 * m;
            bool vl = (gy >= 0) & (gy < H) & (gx >= 0) & (gx <= W - 4);
            float4 val = *(const float4*)(ip + (vl ? ((long)gy * W + gx) : 0));
            float msk = vl ? 1.f : 0.f;
            int off = row * SROW + 4 * m + 4 * (m >> 1);
            *(float4*)&tile[off] = make_float4(val.x * msk, val.y * msk,
                                               val.z * msk, val.w * msk);
        }
    }
    __syncthreads();

    int lane = tid & 63;
    int lx = lane & 7, ly = lane >> 3;

    float acc[4][4];
#pragma unroll
    for (int o = 0; o < 4; ++o)
#pragma unroll
        for (int dx = 0; dx < 4; ++dx) acc[o][dx] = 0.f;

#pragma unroll
    for (int r = 0; r < 11; ++r) {
        int base = (8 * ly + r) * SROW + 12 * lx;
        float4 A = *(const float4*)&tile[base];
        float4 B = *(const float4*)&tile[base + 4];
        float4 C = *(const float4*)&tile[base + 12];
        float4 Dd = *(const float4*)&tile[base + 16];
        float P[16] = {A.x, A.y, A.z, A.w, B.x, B.y, B.z, B.w,
                       C.x, C.y, C.z, C.w, Dd.x, Dd.y, Dd.z, Dd.w};

#pragma unroll
        for (int o = 0; o < 4; ++o) {
            int i = r - 2 * o;
            if (i < 0 || i > 4) continue;
#pragma unroll
            for (int j = 0; j < 5; ++j) {
                float wv = Wt[i * 5 + j];
#pragma unroll
                for (int dx = 0; dx < 4; ++dx)
                    acc[o][dx] = fmaf(P[2 + 2 * dx + j], wv, acc[o][dx]);
            }
        }
    }

    long cs = (long)OH * OW;
    int oy = 32 * by + 4 * ly, ox = 32 * bx + 4 * lx;
    if (w == 0) {
        long ob = (long)n * cs + (long)oy * OW + ox;
#pragma unroll
        for (int o = 0; o < 4; ++o)
            *(float4*)(outc0 + ob + (long)o * OW) =
                make_float4(acc[o][0], acc[o][1], acc[o][2], acc[o][3]);
    } else {
        long ob = ((long)n * 7 + (w - 1)) * cs + (long)oy * OW + ox;
#pragma unroll
        for (int o = 0; o < 4; ++o) {
            ushort4 u;
            u.x = f2bf(acc[o][0]); u.y = f2bf(acc[o][1]);
            u.z = f2bf(acc[o][2]); u.w = f2bf(acc[o][3]);
            *(ushort4*)(outb + ob + (long)o * OW) = u;
        }
    }
}

// -------- forward, wave-per-channel (exact R12 version), fp32 out: levels 2-4 --------
__global__ void fwd_conv_wave_kernel(const float* __restrict__ in, long in_img_stride,
                                     const float* __restrict__ filt,
                                     float* __restrict__ out,
                                     int H, int W, int OH, int OW, int N) {
    constexpr int SROW = 104;
    __shared__ float tile[67 * SROW];

    int nbx = OW >> 5, nby = OH >> 5;
    unsigned sb = xcd_swz(blockIdx.x, gridDim.x);
    int bx = (int)(sb % nbx);
    unsigned t = sb / nbx;
    int by = (int)(t % nby);
    int n = (int)(t / nby);

    const float* __restrict__ ip = in + (long)n * in_img_stride;
    int tid = threadIdx.x;

    int w = __builtin_amdgcn_readfirstlane(tid >> 6);
    const float* __restrict__ F = filt + w * 25;
    float Wt[25];
#pragma unroll
    for (int k = 0; k < 25; ++k) Wt[k] = F[k];

    int gy0 = 64 * by - 2, gx0 = 64 * bx - 4;
#pragma unroll
    for (int k = 0; k < 3; ++k) {
        int e = tid + k * 512;
        if (e < 67 * 18) {
            int row = e / 18, m = e - row * 18;
            int gy = gy0 + row, gx = gx0 + 4 * m;
            bool vl = (gy >= 0) & (gy < H) & (gx >= 0) & (gx <= W - 4);
            float4 val = *(const float4*)(ip + (vl ? ((long)gy * W + gx) : 0));
            float msk = vl ? 1.f : 0.f;
            int off = row * SROW + 4 * m + 4 * (m >> 1);
            *(float4*)&tile[off] = make_float4(val.x * msk, val.y * msk,
                                               val.z * msk, val.w * msk);
        }
    }
    __syncthreads();

    int lane = tid & 63;
    int lx = lane & 7, ly = lane >> 3;

    float acc[4][4];
#pragma unroll
    for (int o = 0; o < 4; ++o)
#pragma unroll
        for (int dx = 0; dx < 4; ++dx) acc[o][dx] = 0.f;

#pragma unroll
    for (int r = 0; r < 11; ++r) {
        int base = (8 * ly + r) * SROW + 12 * lx;
        float4 A = *(const float4*)&tile[base];
        float4 B = *(const float4*)&tile[base + 4];
        float4 C = *(const float4*)&tile[base + 12];
        float4 Dd = *(const float4*)&tile[base + 16];
        float P[16] = {A.x, A.y, A.z, A.w, B.x, B.y, B.z, B.w,
                       C.x, C.y, C.z, C.w, Dd.x, Dd.y, Dd.z, Dd.w};

#pragma unroll
        for (int o = 0; o < 4; ++o) {
            int i = r - 2 * o;
            if (i < 0 || i > 4) continue;
#pragma unroll
            for (int j = 0; j < 5; ++j) {
                float wv = Wt[i * 5 + j];
#pragma unroll
                for (int dx = 0; dx < 4; ++dx)
                    acc[o][dx] = fmaf(P[2 + 2 * dx + j], wv, acc[o][dx]);
            }
        }
    }

    long cs = (long)OH * OW;
    int oy = 32 * by + 4 * ly, ox = 32 * bx + 4 * lx;
    long ob = ((long)n * NORIENT + w) * cs + (long)oy * OW + ox;
#pragma unroll
    for (int o = 0; o < 4; ++o)
        *(float4*)(out + ob + (long)o * OW) =
            make_float4(acc[o][0], acc[o][1], acc[o][2], acc[o][3]);
}

// -------- inverse direct (exact R4/R12 version), fp32 coefs: levels 1-3 --------
__global__ void inv_tconv_kernel(const float* __restrict__ rec, long rec_img_stride,
                                 const float* __restrict__ coef,
                                 const float* __restrict__ filt,
                                 float* __restrict__ out,
                                 int h, int w, int N) {
    int h2 = h >> 1, w2 = w >> 1;
    unsigned sb = xcd_swz(blockIdx.x, gridDim.x);
    long idx = (long)sb * blockDim.x + threadIdx.x;
    long total = (long)N * h2 * w2;
    if (idx >= total) return;
    int b0 = (int)(idx % w2);
    long t = idx / w2;
    int a0 = (int)(t % h2);
    int n = (int)(t / h2);

    const float* __restrict__ rp = rec + (long)n * rec_img_stride;
    const float* __restrict__ cp = coef + (long)n * (long)NORIENT * h * w;
    long cs = (long)h * w;

    bool fmv = a0 > 0, fpv = a0 < h2 - 1;
    bool um = b0 > 0, up = b0 < w2 - 1;
    float fm = fmv ? 1.f : 0.f, fp_ = fpv ? 1.f : 0.f;
    int r0 = (fmv ? 2 * a0 - 1 : 0) * w;
    int r1 = (2 * a0) * w;
    int r2 = (2 * a0 + 1) * w;
    int r3 = (fpv ? 2 * a0 + 2 : 2 * a0 + 1) * w;
    int cL = um ? 2 * b0 - 2 : 0;
    int cM = 2 * b0;
    int cR = up ? 2 * b0 + 2 : 0;

    float acc[2][2][2][2];
#pragma unroll
    for (int i = 0; i < 2; ++i)
#pragma unroll
        for (int j = 0; j < 2; ++j)
#pragma unroll
            for (int k = 0; k < 2; ++k)
#pragma unroll
                for (int l = 0; l < 2; ++l) acc[i][j][k][l] = 0.f;

    auto do_channel = [&](const float* __restrict__ src, const float* __restrict__ F) {
        float P[4][4];
        const int ro[4] = {r0, r1, r2, r3};
        const float rm[4] = {fm, 1.f, 1.f, fp_};
#pragma unroll
        for (int r = 0; r < 4; ++r) {
            const float* base = src + ro[r];
            float2 L = *(const float2*)(base + cL);
            float2 M = *(const float2*)(base + cM);
            float2 R = *(const float2*)(base + cR);
            float mask = rm[r];
            P[r][0] = (um ? L.y : 0.f) * mask;
            P[r][1] = M.x * mask;
            P[r][2] = M.y * mask;
            P[r][3] = (up ? R.x : 0.f) * mask;
        }
#pragma unroll
        for (int a = 0; a < 3; ++a) {
#pragma unroll
            for (int b = 0; b < 3; ++b) {
                float w00 = F[(4 - 2 * a) * 5 + (4 - 2 * b)];
                float w01 = (b >= 1) ? F[(4 - 2 * a) * 5 + (5 - 2 * b)] : 0.f;
                float w10 = (a >= 1) ? F[(5 - 2 * a) * 5 + (4 - 2 * b)] : 0.f;
                float w11 = (a >= 1 && b >= 1) ? F[(5 - 2 * a) * 5 + (5 - 2 * b)] : 0.f;
#pragma unroll
                for (int sr = 0; sr < 2; ++sr) {
#pragma unroll
                    for (int sc = 0; sc < 2; ++sc) {
                        float pv = P[sr + a][sc + b];
                        acc[sr][sc][0][0] = fmaf(pv, w00, acc[sr][sc][0][0]);
                        if (b >= 1) acc[sr][sc][0][1] = fmaf(pv, w01, acc[sr][sc][0][1]);
                        if (a >= 1) acc[sr][sc][1][0] = fmaf(pv, w10, acc[sr][sc][1][0]);
                        if (a >= 1 && b >= 1)
                                    acc[sr][sc][1][1] = fmaf(pv, w11, acc[sr][sc][1][1]);
                    }
                }
            }
        }
    };

    do_channel(rp, filt);
#pragma unroll
    for (int c = 1; c < NORIENT; ++c)
        do_channel(cp + (long)c * cs, filt + c * 25);

    int OW = w << 1;
    long ob = (long)n * 4 * cs + (long)(4 * a0) * OW + 4 * b0;
    *(float4*)(out + ob)          = make_float4(acc[0][0][0][0], acc[0][0][0][1],
                                                acc[0][1][0][0], acc[0][1][0][1]);
    *(float4*)(out + ob + OW)     = make_float4(acc[0][0][1][0], acc[0][0][1][1],
                                                acc[0][1][1][0], acc[0][1][1][1]);
    *(float4*)(out + ob + 2 * OW) = make_float4(acc[1][0][0][0], acc[1][0][0][1],
                                                acc[1][1][0][0], acc[1][1][0][1]);
    *(float4*)(out + ob + 3 * OW) = make_float4(acc[1][0][1][0], acc[1][0][1][1],
                                                acc[1][1][1][0], acc[1][1][1][1]);
}

// -------- inverse level 4: rec fp32 + coef ch1-7 in bf16 (L2-resident stream) --------
__global__ void inv_tconv_bf16_kernel(const float* __restrict__ rec, long rec_img_stride,
                                      const unsigned short* __restrict__ coefb, // [n][7][h*w]
                                      const float* __restrict__ filt,
                                      float* __restrict__ out,
                                      int h, int w, int N) {
    int h2 = h >> 1, w2 = w >> 1;
    unsigned sb = xcd_swz(blockIdx.x, gridDim.x);
    long idx = (long)sb * blockDim.x + threadIdx.x;
    long total = (long)N * h2 * w2;
    if (idx >= total) return;
    int b0 = (int)(idx % w2);
    long t = idx / w2;
    int a0 = (int)(t % h2);
    int n = (int)(t / h2);

    const float* __restrict__ rp = rec + (long)n * rec_img_stride;
    long cs = (long)h * w;
    const unsigned short* __restrict__ cpb = coefb + (long)n * 7 * cs;

    bool fmv = a0 > 0, fpv = a0 < h2 - 1;
    bool um = b0 > 0, up = b0 < w2 - 1;
    float fm = fmv ? 1.f : 0.f, fp_ = fpv ? 1.f : 0.f;
    int r0 = (fmv ? 2 * a0 - 1 : 0) * w;
    int r1 = (2 * a0) * w;
    int r2 = (2 * a0 + 1) * w;
    int r3 = (fpv ? 2 * a0 + 2 : 2 * a0 + 1) * w;
    int cL = um ? 2 * b0 - 2 : 0;
    int cM = 2 * b0;
    int cR = up ? 2 * b0 + 2 : 0;

    const int ro[4] = {r0, r1, r2, r3};
    const float rm[4] = {fm, 1.f, 1.f, fp_};

    float acc[2][2][2][2];
#pragma unroll
    for (int i = 0; i < 2; ++i)
#pragma unroll
        for (int j = 0; j < 2; ++j)
#pragma unroll
            for (int k = 0; k < 2; ++k)
#pragma unroll
                for (int l = 0; l < 2; ++l) acc[i][j][k][l] = 0.f;

    auto accum = [&](const float P[4][4], const float* __restrict__ F) {
#pragma unroll
        for (int a = 0; a < 3; ++a) {
#pragma unroll
            for (int b = 0; b < 3; ++b) {
                float w00 = F[(4 - 2 * a) * 5 + (4 - 2 * b)];
                float w01 = (b >= 1) ? F[(4 - 2 * a) * 5 + (5 - 2 * b)] : 0.f;
                float w10 = (a >= 1) ? F[(5 - 2 * a) * 5 + (4 - 2 * b)] : 0.f;
                float w11 = (a >= 1 && b >= 1) ? F[(5 - 2 * a) * 5 + (5 - 2 * b)] : 0.f;
#pragma unroll
                for (int sr = 0; sr < 2; ++sr) {
#pragma unroll
                    for (int sc = 0; sc < 2; ++sc) {
                        float pv = P[sr + a][sc + b];
                        acc[sr][sc][0][0] = fmaf(pv, w00, acc[sr][sc][0][0]);
                        if (b >= 1) acc[sr][sc][0][1] = fmaf(pv, w01, acc[sr][sc][0][1]);
                        if (a >= 1) acc[sr][sc][1][0] = fmaf(pv, w10, acc[sr][sc][1][0]);
                        if (a >= 1 && b >= 1)
                                    acc[sr][sc][1][1] = fmaf(pv, w11, acc[sr][sc][1][1]);
                    }
                }
            }
        }
    };

    {   // channel 0 from rec (fp32)
        float P[4][4];
#pragma unroll
        for (int r = 0; r < 4; ++r) {
            const float* base = rp + ro[r];
            float2 L = *(const float2*)(base + cL);
            float2 M = *(const float2*)(base + cM);
            float2 R = *(const float2*)(base + cR);
            float mask = rm[r];
            P[r][0] = (um ? L.y : 0.f) * mask;
            P[r][1] = M.x * mask;
            P[r][2] = M.y * mask;
            P[r][3] = (up ? R.x : 0.f) * mask;
        }
        accum(P, filt);
    }

#pragma unroll
    for (int c = 1; c < NORIENT; ++c) {   // channels 1-7 from bf16
        const unsigned short* __restrict__ src = cpb + (long)(c - 1) * cs;
        float P[4][4];
#pragma unroll
        for (int r = 0; r < 4; ++r) {
            const unsigned short* base = src + ro[r];
            ushort2 L = *(const ushort2*)(base + cL);
            ushort2 M = *(const ushort2*)(base + cM);
            ushort2 R = *(const ushort2*)(base + cR);
            float mask = rm[r];
            P[r][0] = (um ? bf2f(L.y) : 0.f) * mask;
            P[r][1] = bf2f(M.x) * mask;
            P[r][2] = bf2f(M.y) * mask;
            P[r][3] = (up ? bf2f(R.x) : 0.f) * mask;
        }
        accum(P, filt + c * 25);
    }

    int OW = w << 1;
    long ob = (long)n * 4 * cs + (long)(4 * a0) * OW + 4 * b0;
    *(float4*)(out + ob)          = make_float4(acc[0][0][0][0], acc[0][0][0][1],
                                                acc[0][1][0][0], acc[0][1][0][1]);
    *(float4*)(out + ob + OW)     = make_float4(acc[0][0][1][0], acc[0][0][1][1],
                                                acc[0][1][1][0], acc[0][1][1][1]);
    *(float4*)(out + ob + 2 * OW) = make_float4(acc[1][0][0][0], acc[1][0][0][1],
                                                acc[1][1][0][0], acc[1][1][0][1]);
    *(float4*)(out + ob + 3 * OW) = make_float4(acc[1][0][1][0], acc[1][0][1][1],
                                                acc[1][1][1][0], acc[1][1][1][1]);
}

extern "C" void kernel_launch(void* const* d_in, const int* in_sizes, int n_in,
                              void* d_out, int out_size, void* d_ws, size_t ws_size,
                              hipStream_t stream) {
    const float* x     = (const float*)d_in[0];
    const float* fwd_f = (const float*)d_in[1];
    const float* inv_f = (const float*)d_in[2];
    float* out = (float*)d_out;
    float* ws  = (float*)d_ws;

    const int N = 32;

    // workspace layout (floats unless noted) — all offsets multiples of 4
    float* l4c0 = ws;                                   // 32*256*256      = 2,097,152 fp32
    unsigned short* l4b = (unsigned short*)(ws + 2097152); // 32*7*256*256 = 14,680,064 bf16 (=7,340,032 fl)
    float* l3 = ws + 2097152 + 7340032;                 // 32*8*128*128   = 4,194,304
    float* l2 = l3 + 4194304;                           // 32*8*64*64     = 1,048,576
    float* l1 = l2 + 1048576;                           // 32*8*32*32     =   262,144
    float* r1 = l1 + 262144;                            // 32*64*64       =   131,072
    float* r2 = r1 + 131072;                            // 32*128*128     =   524,288
    float* r3 = r2 + 524288;                            // 32*256*256     = 2,097,152

    dim3 blkF(512), blk(256);
    auto nblocks = [](long total) { return dim3((unsigned)((total + 255) / 256)); };

    // ---- forward transform: wave-per-channel ----
    fwd_conv_wave_l1_kernel<<<dim3(32 * 8 * 8), blkF, 0, stream>>>(
        x, 512L * 512, fwd_f, l4c0, l4b, 512, 512, 256, 256, N);
    fwd_conv_wave_kernel<<<dim3(32 * 4 * 4), blkF, 0, stream>>>(
        l4c0, 65536L, fwd_f, l3, 256, 256, 128, 128, N);
    fwd_conv_wave_kernel<<<dim3(32 * 2 * 2), blkF, 0, stream>>>(
        l3, 8L * 128 * 128, fwd_f, l2, 128, 128, 64, 64, N);
    fwd_conv_wave_kernel<<<dim3(32 * 1 * 1), blkF, 0, stream>>>(
        l2, 8L * 64 * 64, fwd_f, l1, 64, 64, 32, 32, N);

    // ---- inverse transform ----
    inv_tconv_kernel<<<nblocks(32L * 16 * 16), blk, 0, stream>>>(
        l1, 8L * 32 * 32, l1, inv_f, r1, 32, 32, N);
    inv_tconv_kernel<<<nblocks(32L * 32 * 32), blk, 0, stream>>>(
        r1, 64L * 64, l2, inv_f, r2, 64, 64, N);
    inv_tconv_kernel<<<nblocks(32L * 64 * 64), blk, 0, stream>>>(
        r2, 128L * 128, l3, inv_f, r3, 128, 128, N);
    inv_tconv_bf16_kernel<<<nblocks(32L * 128 * 128), blk, 0, stream>>>(
        r3, 256L * 256, l4b, inv_f, out, 256, 256, N);
}

// Round 17
// 96.579 us; speedup vs baseline: 1.1017x; 1.1017x over previous
//
#include <hip/hip_runtime.h>

#define NORIENT 8

// XCD-aware block swizzle (bijective when gridDim % 8 == 0; all our grids are).
__device__ __forceinline__ unsigned xcd_swz(unsigned bid, unsigned nwg) {
    unsigned chunk = nwg >> 3;
    return (nwg & 7u) ? bid : (bid & 7u) * chunk + (bid >> 3);
}

// -------- forward, wave-per-channel: stride-2 5x5 conv, 1 -> 8 ch --------
// Block = 512 threads = 8 waves; wave w computes channel w only -> its 25
// weights are hoisted into SGPRs ONCE (readfirstlane-uniform base): the
// 800-FMA body has ZERO scalar/global loads. Output tile 32x32; lane (lx,ly)
// -> 4x4 outputs. LDS layout col c -> c + 4*(c>>3) (SROW=104) spreads the
// 32B lane stride across banks (2-way = free). [R12-proven, best fwd]
__global__ void fwd_conv_wave_kernel(const float* __restrict__ in, long in_img_stride,
                                     const float* __restrict__ filt,
                                     float* __restrict__ out,
                                     int H, int W, int OH, int OW, int N) {
    constexpr int SROW = 104;
    __shared__ float tile[67 * SROW];      // 27,872 B

    int nbx = OW >> 5, nby = OH >> 5;
    unsigned sb = xcd_swz(blockIdx.x, gridDim.x);
    int bx = (int)(sb % nbx);
    unsigned t = sb / nbx;
    int by = (int)(t % nby);
    int n = (int)(t / nby);

    const float* __restrict__ ip = in + (long)n * in_img_stride;
    int tid = threadIdx.x;

    int w = __builtin_amdgcn_readfirstlane(tid >> 6);
    const float* __restrict__ F = filt + w * 25;
    float Wt[25];
#pragma unroll
    for (int k = 0; k < 25; ++k) Wt[k] = F[k];

    int gy0 = 64 * by - 2, gx0 = 64 * bx - 4;
#pragma unroll
    for (int k = 0; k < 3; ++k) {
        int e = tid + k * 512;
        if (e < 67 * 18) {
            int row = e / 18, m = e - row * 18;
            int gy = gy0 + row, gx = gx0 + 4 * m;
            bool vl = (gy >= 0) & (gy < H) & (gx >= 0) & (gx <= W - 4);
            float4 val = *(const float4*)(ip + (vl ? ((long)gy * W + gx) : 0));
            float msk = vl ? 1.f : 0.f;
            int off = row * SROW + 4 * m + 4 * (m >> 1);
            *(float4*)&tile[off] = make_float4(val.x * msk, val.y * msk,
                                               val.z * msk, val.w * msk);
        }
    }
    __syncthreads();

    int lane = tid & 63;
    int lx = lane & 7, ly = lane >> 3;

    float acc[4][4];
#pragma unroll
    for (int o = 0; o < 4; ++o)
#pragma unroll
        for (int dx = 0; dx < 4; ++dx) acc[o][dx] = 0.f;

#pragma unroll
    for (int r = 0; r < 11; ++r) {
        int base = (8 * ly + r) * SROW + 12 * lx;
        float4 A = *(const float4*)&tile[base];
        float4 B = *(const float4*)&tile[base + 4];
        float4 C = *(const float4*)&tile[base + 12];
        float4 Dd = *(const float4*)&tile[base + 16];
        float P[16] = {A.x, A.y, A.z, A.w, B.x, B.y, B.z, B.w,
                       C.x, C.y, C.z, C.w, Dd.x, Dd.y, Dd.z, Dd.w};

#pragma unroll
        for (int o = 0; o < 4; ++o) {
            int i = r - 2 * o;
            if (i < 0 || i > 4) continue;
#pragma unroll
            for (int j = 0; j < 5; ++j) {
                float wv = Wt[i * 5 + j];
#pragma unroll
                for (int dx = 0; dx < 4; ++dx)
                    acc[o][dx] = fmaf(P[2 + 2 * dx + j], wv, acc[o][dx]);
            }
        }
    }

    long cs = (long)OH * OW;
    int oy = 32 * by + 4 * ly, ox = 32 * bx + 4 * lx;
    long ob = ((long)n * NORIENT + w) * cs + (long)oy * OW + ox;
#pragma unroll
    for (int o = 0; o < 4; ++o)
        *(float4*)(out + ob + (long)o * OW) =
            make_float4(acc[o][0], acc[o][1], acc[o][2], acc[o][3]);
}

// -------- inverse direct: transposed conv, 8 -> 1 channel, stride 2 --------
// Thread owns a 2x2 block of coefficient sites -> 4x4 output block. Per
// channel: 4 rows x 3 aligned loads (12 VMEM). Stores are 4x float4,
// lane-contiguous per instruction (WRITE_SIZE == output, R2/R4-proven).
// [Exact R4/R12 version — every restructuring attempt (LDS tile, channel
// split, bf16 coefs) measured slower; see R13-R16 post-mortems.]
__global__ void inv_tconv_kernel(const float* __restrict__ rec, long rec_img_stride,
                                 const float* __restrict__ coef,
                                 const float* __restrict__ filt,
                                 float* __restrict__ out,
                                 int h, int w, int N) {
    int h2 = h >> 1, w2 = w >> 1;
    unsigned sb = xcd_swz(blockIdx.x, gridDim.x);
    long idx = (long)sb * blockDim.x + threadIdx.x;
    long total = (long)N * h2 * w2;
    if (idx >= total) return;
    int b0 = (int)(idx % w2);
    long t = idx / w2;
    int a0 = (int)(t % h2);
    int n = (int)(t / h2);

    const float* __restrict__ rp = rec + (long)n * rec_img_stride;
    const float* __restrict__ cp = coef + (long)n * (long)NORIENT * h * w;
    long cs = (long)h * w;

    bool fmv = a0 > 0, fpv = a0 < h2 - 1;
    bool um = b0 > 0, up = b0 < w2 - 1;
    float fm = fmv ? 1.f : 0.f, fp_ = fpv ? 1.f : 0.f;
    int r0 = (fmv ? 2 * a0 - 1 : 0) * w;
    int r1 = (2 * a0) * w;
    int r2 = (2 * a0 + 1) * w;
    int r3 = (fpv ? 2 * a0 + 2 : 2 * a0 + 1) * w;
    int cL = um ? 2 * b0 - 2 : 0;
    int cM = 2 * b0;
    int cR = up ? 2 * b0 + 2 : 0;

    float acc[2][2][2][2];  // [sr][sc][dy][dx]
#pragma unroll
    for (int i = 0; i < 2; ++i)
#pragma unroll
        for (int j = 0; j < 2; ++j)
#pragma unroll
            for (int k = 0; k < 2; ++k)
#pragma unroll
                for (int l = 0; l < 2; ++l) acc[i][j][k][l] = 0.f;

    auto do_channel = [&](const float* __restrict__ src, const float* __restrict__ F) {
        float P[4][4];
        const int ro[4] = {r0, r1, r2, r3};
        const float rm[4] = {fm, 1.f, 1.f, fp_};
#pragma unroll
        for (int r = 0; r < 4; ++r) {
            const float* base = src + ro[r];
            float2 L = *(const float2*)(base + cL);
            float2 M = *(const float2*)(base + cM);
            float2 R = *(const float2*)(base + cR);
            float mask = rm[r];
            P[r][0] = (um ? L.y : 0.f) * mask;
            P[r][1] = M.x * mask;
            P[r][2] = M.y * mask;
            P[r][3] = (up ? R.x : 0.f) * mask;
        }
#pragma unroll
        for (int a = 0; a < 3; ++a) {
#pragma unroll
            for (int b = 0; b < 3; ++b) {
                float w00 = F[(4 - 2 * a) * 5 + (4 - 2 * b)];
                float w01 = (b >= 1) ? F[(4 - 2 * a) * 5 + (5 - 2 * b)] : 0.f;
                float w10 = (a >= 1) ? F[(5 - 2 * a) * 5 + (4 - 2 * b)] : 0.f;
                float w11 = (a >= 1 && b >= 1) ? F[(5 - 2 * a) * 5 + (5 - 2 * b)] : 0.f;
#pragma unroll
                for (int sr = 0; sr < 2; ++sr) {
#pragma unroll
                    for (int sc = 0; sc < 2; ++sc) {
                        float pv = P[sr + a][sc + b];
                        acc[sr][sc][0][0] = fmaf(pv, w00, acc[sr][sc][0][0]);
                        if (b >= 1) acc[sr][sc][0][1] = fmaf(pv, w01, acc[sr][sc][0][1]);
                        if (a >= 1) acc[sr][sc][1][0] = fmaf(pv, w10, acc[sr][sc][1][0]);
                        if (a >= 1 && b >= 1)
                                    acc[sr][sc][1][1] = fmaf(pv, w11, acc[sr][sc][1][1]);
                    }
                }
            }
        }
    };

    do_channel(rp, filt);
#pragma unroll
    for (int c = 1; c < NORIENT; ++c)
        do_channel(cp + (long)c * cs, filt + c * 25);

    int OW = w << 1;
    long ob = (long)n * 4 * cs + (long)(4 * a0) * OW + 4 * b0;
    *(float4*)(out + ob)          = make_float4(acc[0][0][0][0], acc[0][0][0][1],
                                                acc[0][1][0][0], acc[0][1][0][1]);
    *(float4*)(out + ob + OW)     = make_float4(acc[0][0][1][0], acc[0][0][1][1],
                                                acc[0][1][1][0], acc[0][1][1][1]);
    *(float4*)(out + ob + 2 * OW) = make_float4(acc[1][0][0][0], acc[1][0][0][1],
                                                acc[1][1][0][0], acc[1][1][0][1]);
    *(float4*)(out + ob + 3 * OW) = make_float4(acc[1][0][1][0], acc[1][0][1][1],
                                                acc[1][1][1][0], acc[1][1][1][1]);
}

extern "C" void kernel_launch(void* const* d_in, const int* in_sizes, int n_in,
                              void* d_out, int out_size, void* d_ws, size_t ws_size,
                              hipStream_t stream) {
    const float* x     = (const float*)d_in[0];
    const float* fwd_f = (const float*)d_in[1];
    const float* inv_f = (const float*)d_in[2];
    float* out = (float*)d_out;
    float* ws  = (float*)d_ws;

    const int N = 32;

    // workspace layout (floats) — all offsets multiples of 4 -> 16B aligned
    float* l4 = ws;                  // 32*8*256*256 = 16,777,216
    float* l3 = l4 + 16777216;       // 32*8*128*128 =  4,194,304
    float* l2 = l3 + 4194304;        // 32*8*64*64   =  1,048,576
    float* l1 = l2 + 1048576;        // 32*8*32*32   =    262,144
    float* r1 = l1 + 262144;         // 32*64*64     =    131,072
    float* r2 = r1 + 131072;         // 32*128*128   =    524,288
    float* r3 = r2 + 524288;         // 32*256*256   =  2,097,152

    dim3 blkF(512), blk(256);
    auto nblocks = [](long total) { return dim3((unsigned)((total + 255) / 256)); };

    // ---- forward transform: wave-per-channel, grid = N * (OH/32) * (OW/32) ----
    fwd_conv_wave_kernel<<<dim3(32 * 8 * 8), blkF, 0, stream>>>(
        x, 512L * 512, fwd_f, l4, 512, 512, 256, 256, N);
    fwd_conv_wave_kernel<<<dim3(32 * 4 * 4), blkF, 0, stream>>>(
        l4, 8L * 256 * 256, fwd_f, l3, 256, 256, 128, 128, N);
    fwd_conv_wave_kernel<<<dim3(32 * 2 * 2), blkF, 0, stream>>>(
        l3, 8L * 128 * 128, fwd_f, l2, 128, 128, 64, 64, N);
    fwd_conv_wave_kernel<<<dim3(32 * 1 * 1), blkF, 0, stream>>>(
        l2, 8L * 64 * 64, fwd_f, l1, 64, 64, 32, 32, N);

    // ---- inverse transform (threads = N * h/2 * w/2) ----
    inv_tconv_kernel<<<nblocks(32L * 16 * 16), blk, 0, stream>>>(
        l1, 8L * 32 * 32, l1, inv_f, r1, 32, 32, N);
    inv_tconv_kernel<<<nblocks(32L * 32 * 32), blk, 0, stream>>>(
        r1, 64L * 64, l2, inv_f, r2, 64, 64, N);
    inv_tconv_kernel<<<nblocks(32L * 64 * 64), blk, 0, stream>>>(
        r2, 128L * 128, l3, inv_f, r3, 128, 128, N);
    inv_tconv_kernel<<<nblocks(32L * 128 * 128), blk, 0, stream>>>(
        r3, 256L * 256, l4, inv_f, out, 256, 256, N);
}